// Round 12
// baseline (87.998 us; speedup 1.0000x reference)
//
#include <hip/hip_runtime.h>
#include <hip/hip_bf16.h>
#include <hip/hip_fp16.h>

#define C 128        // C_IN == C_OUT == 128
#define NCH 32768    // nodes per LDS chunk (2^15), u8-packed counters -> 32 KiB LDS
#define CN 2         // chunks: 2*32768 = 65536 >= n (50000)
#define CNODES (CN * NCH)
#define BE 128       // edge chunks per side

typedef _Float16 f16x8 __attribute__((ext_vector_type(8)));
typedef _Float16 f16x4 __attribute__((ext_vector_type(4)));
typedef float f32x4 __attribute__((ext_vector_type(4)));

// ============================================================================
// Dispatch 1: blocks [0,GB): MFMA GEMM y16 = x @ W^T (fp16, UNSCALED);
//             blocks [GB, GB+CN*BE): row hist + u8 rank tags;
//             blocks [GB+CN*BE, GB+2*CN*BE): col hist (degree).
// GEMM first: it's the long pole; hist hides under it.
// ============================================================================
__global__ __launch_bounds__(256) void k_hist_gemm(
        const int* __restrict__ row, const int* __restrict__ col,
        unsigned char* __restrict__ part_row, unsigned char* __restrict__ part_col,
        unsigned char* __restrict__ tag, int E, int EPB, int GB,
        const float* __restrict__ A, const float* __restrict__ W,
        __half* __restrict__ Y16, int n) {
    __shared__ char lds[128 * 256];  // 32 KiB; hist uses first 32 KiB as counters
    int bid = blockIdx.x;
    int tid = threadIdx.x;

    if (bid >= GB) {
        // ---------------- histogram side ----------------
        unsigned* lh = (unsigned*)lds;     // NCH/4 = 8192 words = 32 KiB
        int lb = bid - GB;
        int side = (lb >= CN * BE) ? 1 : 0;
        if (side) lb -= CN * BE;
        int c = lb >> 7;          // / BE  (0..CN-1)
        int b = lb & (BE - 1);
        for (int i = tid * 4; i < NCH / 4; i += 1024) {
            lh[i] = 0u; lh[i + 1] = 0u; lh[i + 2] = 0u; lh[i + 3] = 0u;
        }
        __syncthreads();
        int base = b * EPB;
        int end = min(base + EPB, E);
        const int* src = side ? col : row;

#define PROC_ROW(rv, ev)                                                  \
    if (((unsigned)(rv) >> 15) == (unsigned)c) {                          \
        int loc = (rv) & (NCH - 1);                                       \
        unsigned sh = ((unsigned)loc & 3u) << 3;                          \
        unsigned old = atomicAdd(&lh[loc >> 2], 1u << sh);                \
        tag[ev] = (unsigned char)((old >> sh) & 0xffu);                   \
    }
#define PROC_COL(rv)                                                      \
    if (((unsigned)(rv) >> 15) == (unsigned)c) {                          \
        int loc = (rv) & (NCH - 1);                                       \
        atomicAdd(&lh[loc >> 2], 1u << (((unsigned)loc & 3u) << 3));      \
    }
        int nv = (end > base) ? ((end - base) >> 2) : 0;  // EPB %4==0 -> aligned
        const int4* src4 = (const int4*)(src + base);
        if (!side) {
            for (int it = tid; it < nv; it += 256) {
                int4 v = src4[it];
                int e0 = base + it * 4;
                PROC_ROW(v.x, e0);
                PROC_ROW(v.y, e0 + 1);
                PROC_ROW(v.z, e0 + 2);
                PROC_ROW(v.w, e0 + 3);
            }
            for (int e = base + nv * 4 + tid; e < end; e += 256) {
                int r = src[e];
                PROC_ROW(r, e);
            }
        } else {
            for (int it = tid; it < nv; it += 256) {
                int4 v = src4[it];
                PROC_COL(v.x);
                PROC_COL(v.y);
                PROC_COL(v.z);
                PROC_COL(v.w);
            }
            for (int e = base + nv * 4 + tid; e < end; e += 256) {
                int r = src[e];
                PROC_COL(r);
            }
        }
#undef PROC_ROW
#undef PROC_COL
        __syncthreads();
        unsigned* dst = (unsigned*)((side ? part_col : part_row) + (size_t)b * CNODES + c * NCH);
        for (int i = tid; i < NCH / 4; i += 256) dst[i] = lh[i];
        return;
    }

    // ---------------- GEMM (unscaled fp16 output) ----------------
    int w = tid >> 6, lane = tid & 63;
    int m0 = bid * 128;

#pragma unroll
    for (int i = 0; i < 16; ++i) {
        int fidx = i * 256 + tid;
        int nr = fidx >> 5;
        int c4 = fidx & 31;
        float4 wv = *(const float4*)(W + (size_t)nr * C + c4 * 4);
        f16x4 hh = {(_Float16)wv.x, (_Float16)wv.y, (_Float16)wv.z, (_Float16)wv.w};
        unsigned byte = (unsigned)(nr * 256 + c4 * 8);
        byte ^= (unsigned)((nr & 7) << 4);
        *(f16x4*)(lds + byte) = hh;
    }
    __syncthreads();

    int rbase = m0 + w * 32;
    int q = lane >> 4, rl = lane & 15;
    f32x4 acc[2][8] = {};
#pragma unroll
    for (int kc = 0; kc < 4; ++kc) {
        f16x8 af[2];
#pragma unroll
        for (int mt = 0; mt < 2; ++mt) {
            int r = rbase + mt * 16 + rl;
            float4 x0 = make_float4(0.f, 0.f, 0.f, 0.f), x1 = x0;
            if (r < n) {
                const float* srcx = A + (size_t)r * C + kc * 32 + q * 8;
                x0 = *(const float4*)srcx;
                x1 = *(const float4*)(srcx + 4);
            }
            af[mt][0] = (_Float16)x0.x;
            af[mt][1] = (_Float16)x0.y;
            af[mt][2] = (_Float16)x0.z;
            af[mt][3] = (_Float16)x0.w;
            af[mt][4] = (_Float16)x1.x;
            af[mt][5] = (_Float16)x1.y;
            af[mt][6] = (_Float16)x1.z;
            af[mt][7] = (_Float16)x1.w;
        }
#pragma unroll
        for (int nt = 0; nt < 8; ++nt) {
            int nrow = nt * 16 + rl;
            unsigned byte = (unsigned)(nrow * 256 + kc * 64 + q * 16);
            byte ^= (unsigned)((nrow & 7) << 4);
            f16x8 bf = *(f16x8*)(lds + byte);
            acc[0][nt] = __builtin_amdgcn_mfma_f32_16x16x32_f16(af[0], bf, acc[0][nt], 0, 0, 0);
            acc[1][nt] = __builtin_amdgcn_mfma_f32_16x16x32_f16(af[1], bf, acc[1][nt], 0, 0, 0);
        }
    }
    __syncthreads();

#pragma unroll
    for (int mt = 0; mt < 2; ++mt)
#pragma unroll
        for (int nt = 0; nt < 8; ++nt)
#pragma unroll
            for (int i = 0; i < 4; ++i) {
                int row_l = w * 32 + mt * 16 + q * 4 + i;
                int colh = nt * 16 + rl;
                unsigned byte = (unsigned)(row_l * 256 + colh * 2);
                byte ^= (unsigned)((row_l & 7) << 4);
                *(_Float16*)(lds + byte) = (_Float16)acc[mt][nt][i];
            }
    __syncthreads();

#pragma unroll
    for (int it = 0; it < 8; ++it) {
        int idx = it * 256 + tid;
        int row_l = idx >> 4, c8 = idx & 15;
        unsigned byte = (unsigned)(row_l * 256 + c8 * 16);
        byte ^= (unsigned)((row_l & 7) << 4);
        uint4 v = *(uint4*)(lds + byte);
        int gr = m0 + row_l;
        if (gr < n) *(uint4*)(Y16 + (size_t)gr * C + c8 * 8) = v;
    }
}

// ---- per-node: row total + in-place exclusive u8 offsets; dis; block scan ----
__global__ __launch_bounds__(256) void k_reduce_scan(
        unsigned char* __restrict__ part_row, const unsigned char* __restrict__ part_col,
        unsigned* __restrict__ start, unsigned* __restrict__ bsum,
        float* __restrict__ dis, int n) {
    __shared__ unsigned s[256];
    int t = threadIdx.x;
    int i = blockIdx.x * 256 + t;
    unsigned acc = 0;
    if (i < n) {
#pragma unroll 8
        for (int b = 0; b < BE; ++b) {
            size_t off = (size_t)b * CNODES + i;
            unsigned v = part_row[off];
            part_row[off] = (unsigned char)acc;
            acc += v;
        }
        unsigned d = 0;
#pragma unroll 8
        for (int b = 0; b < BE; ++b) d += part_col[(size_t)b * CNODES + i];
        dis[i] = rsqrtf((float)(d + 1u));
    }
    unsigned v = acc;
    s[t] = v;
    __syncthreads();
    for (int off = 1; off < 256; off <<= 1) {
        unsigned add = (t >= off) ? s[t - off] : 0u;
        __syncthreads();
        s[t] += add;
        __syncthreads();
    }
    if (i < n) start[i] = s[t] - v;      // exclusive within block
    if (t == 255) bsum[blockIdx.x] = s[t];
}

// ---- finalize: start[i] += sum(bsum[0..bid)); start[n] = E ----
__global__ __launch_bounds__(256) void k_scan_final(unsigned* __restrict__ start,
                                                    const unsigned* __restrict__ bsum,
                                                    int n, int E) {
    __shared__ unsigned s[256];
    int t = threadIdx.x;
    int bid = blockIdx.x;
    s[t] = (t < bid) ? bsum[t] : 0u;     // NB <= 256
    __syncthreads();
    for (int off = 128; off > 0; off >>= 1) {
        if (t < off) s[t] += s[t + off];
        __syncthreads();
    }
    unsigned base = s[0];
    int i = bid * 256 + t;
    if (i < n) start[i] += base;
    if (i == n) start[i] = (unsigned)E;
}

// ============================================================================
// Dispatch 4: blocks [0,SB): atomic-free scatter;
//             blocks [SB,SB+ZB): in-place scale z16[r][:] *= dis[r] (uint4 RMW)
// ============================================================================
__global__ __launch_bounds__(256) void k_scatter_scale(
        const int* __restrict__ row, const int* __restrict__ col,
        const unsigned char* __restrict__ tag, const unsigned char* __restrict__ boff,
        const unsigned* __restrict__ start, int* __restrict__ scol,
        int E, int EPB, int SB,
        __half* __restrict__ Z16, const float* __restrict__ dis, int n) {
    int bid = blockIdx.x;
    int tid = threadIdx.x;
    if (bid < SB) {
        int e = bid * 256 + tid;
        if (e < E) {
            unsigned b = (unsigned)e / (unsigned)EPB;
            int r = row[e];
            unsigned p = start[r] + boff[(size_t)b * CNODES + r] + tag[e];
            scol[p] = col[e];
        }
        return;
    }
    int idx = (bid - SB) * 256 + tid;     // uint4 index: 16 per row
    if (idx < n * 16) {
        int r = idx >> 4;
        float dr = dis[r];
        uint4* Z4 = (uint4*)Z16;
        uint4 v = Z4[idx];
        __half2* hp = (__half2*)&v;
#pragma unroll
        for (int j = 0; j < 4; ++j) {
            float2 f = __half22float2(hp[j]);
            hp[j] = __floats2half2_rn(f.x * dr, f.y * dr);
        }
        Z4[idx] = v;
    }
}

// ============================================================================
// k_agg v3 (round-11, proven): out[r] = b + dis[r]*(z[r] + sum_edges z[col])
// Wave = 4 edge-slots x 16 lanes; lane loads uint4 (8ch) of the 256B z-row.
// ============================================================================
__device__ __forceinline__ void add8(uint4 v, float2& a0, float2& a1,
                                     float2& a2, float2& a3) {
    float2 f;
    f = __half22float2(*(__half2*)&v.x); a0.x += f.x; a0.y += f.y;
    f = __half22float2(*(__half2*)&v.y); a1.x += f.x; a1.y += f.y;
    f = __half22float2(*(__half2*)&v.z); a2.x += f.x; a2.y += f.y;
    f = __half22float2(*(__half2*)&v.w); a3.x += f.x; a3.y += f.y;
}

__global__ __launch_bounds__(256) void k_agg(const __half* __restrict__ Z16,
                                             const int* __restrict__ scol,
                                             const unsigned* __restrict__ start,
                                             const float* __restrict__ dis,
                                             const float* __restrict__ bias,
                                             float* __restrict__ out, int n) {
    int wid = threadIdx.x >> 6;
    int lane = threadIdx.x & 63;
    int slot = lane >> 4;          // 0..3 edge slot
    int g = lane & 15;             // 16 B group within 256 B row
    int r = blockIdx.x * 4 + wid;
    if (r >= n) return;
    unsigned s0 = start[r], s1 = start[r + 1];
    float dr = dis[r];
    const uint4* Z4 = (const uint4*)Z16;   // row stride = 16 uint4
    float2 a0 = {0.f, 0.f}, a1 = a0, a2 = a0, a3 = a0;
    if (slot == 0) {
        uint4 v = Z4[(size_t)r * 16 + g];  // self term
        add8(v, a0, a1, a2, a3);
    }
    unsigned k = s0;
    for (; k + 16 <= s1; k += 16) {
        int c0 = scol[k + slot];
        int c1 = scol[k + 4 + slot];
        int c2 = scol[k + 8 + slot];
        int c3 = scol[k + 12 + slot];
        uint4 v0 = Z4[(size_t)c0 * 16 + g];
        uint4 v1 = Z4[(size_t)c1 * 16 + g];
        uint4 v2 = Z4[(size_t)c2 * 16 + g];
        uint4 v3 = Z4[(size_t)c3 * 16 + g];
        add8(v0, a0, a1, a2, a3);
        add8(v1, a0, a1, a2, a3);
        add8(v2, a0, a1, a2, a3);
        add8(v3, a0, a1, a2, a3);
    }
    for (; k < s1; k += 4) {
        unsigned ke = k + slot;
        if (ke < s1) {
            int c = scol[ke];
            uint4 v = Z4[(size_t)c * 16 + g];
            add8(v, a0, a1, a2, a3);
        }
    }
    a0.x += __shfl_xor(a0.x, 16); a0.y += __shfl_xor(a0.y, 16);
    a1.x += __shfl_xor(a1.x, 16); a1.y += __shfl_xor(a1.y, 16);
    a2.x += __shfl_xor(a2.x, 16); a2.y += __shfl_xor(a2.y, 16);
    a3.x += __shfl_xor(a3.x, 16); a3.y += __shfl_xor(a3.y, 16);
    a0.x += __shfl_xor(a0.x, 32); a0.y += __shfl_xor(a0.y, 32);
    a1.x += __shfl_xor(a1.x, 32); a1.y += __shfl_xor(a1.y, 32);
    a2.x += __shfl_xor(a2.x, 32); a2.y += __shfl_xor(a2.y, 32);
    a3.x += __shfl_xor(a3.x, 32); a3.y += __shfl_xor(a3.y, 32);
    if (slot == 0) {
        float4 b0 = *(const float4*)(bias + g * 8);
        float4 b1 = *(const float4*)(bias + g * 8 + 4);
        float4 o0, o1;
        o0.x = b0.x + dr * a0.x; o0.y = b0.y + dr * a0.y;
        o0.z = b0.z + dr * a1.x; o0.w = b0.w + dr * a1.y;
        o1.x = b1.x + dr * a2.x; o1.y = b1.y + dr * a2.y;
        o1.z = b1.z + dr * a3.x; o1.w = b1.w + dr * a3.y;
        float* op = out + (size_t)r * C + g * 8;
        *(float4*)op = o0;
        *(float4*)(op + 4) = o1;
    }
}

extern "C" void kernel_launch(void* const* d_in, const int* in_sizes, int n_in,
                              void* d_out, int out_size, void* d_ws, size_t ws_size,
                              hipStream_t stream) {
    const float* x  = (const float*)d_in[0];
    const int*   ei = (const int*)d_in[1];   // [2, E] flat
    const float* W  = (const float*)d_in[2];
    const float* b  = (const float*)d_in[3];
    float* out = (float*)d_out;

    int n = in_sizes[0] / C;        // 50000 (requires n <= CNODES = 65536)
    int E = in_sizes[1] / 2;        // 800000
    const int* row = ei;
    const int* col = ei + E;

    // workspace layout (512B-aligned slabs), ~34 MB total
    char* p = (char*)d_ws;
    size_t sz_part = (((size_t)BE * CNODES) + 511) & ~(size_t)511;   // 8 MB (u8)
    size_t sz_n    = (((size_t)n * 4) + 511) & ~(size_t)511;
    size_t sz_n1   = (((size_t)(n + 1) * 4) + 511) & ~(size_t)511;
    size_t sz_E1   = (((size_t)E) + 511) & ~(size_t)511;
    size_t sz_E4   = (((size_t)E * 4) + 511) & ~(size_t)511;
    size_t off = 0;
    unsigned char*  part_row = (unsigned char*)(p + off);  off += sz_part;
    unsigned char*  part_col = (unsigned char*)(p + off);  off += sz_part;
    unsigned*       start    = (unsigned*)(p + off);       off += sz_n1;
    float*          dis      = (float*)(p + off);          off += sz_n;
    unsigned*       bsum     = (unsigned*)(p + off);       off += 4096;
    unsigned char*  tag      = (unsigned char*)(p + off);  off += sz_E1;
    int*            scol     = (int*)(p + off);            off += sz_E4;
    __half*         z16      = (__half*)(p + off);         // n*C halves

    int NT = 256;
    int NB = (n + NT - 1) / NT;                   // 196 <= 256
    int EPB = (((E + BE - 1) / BE) + 3) & ~3;     // 6252, %4==0 (int4 align)
    int SB = (E + NT - 1) / NT;                   // 3125
    int ZB = (n * 16 + NT - 1) / NT;              // 3125
    int GB = (n + 127) / 128;                     // 391

    k_hist_gemm<<<GB + 2 * CN * BE, NT, 0, stream>>>(row, col, part_row, part_col,
                                                     tag, E, EPB, GB, x, W, z16, n);
    k_reduce_scan<<<NB, NT, 0, stream>>>(part_row, part_col, start, bsum, dis, n);
    k_scan_final<<<NB, NT, 0, stream>>>(start, bsum, n, E);
    k_scatter_scale<<<SB + ZB, NT, 0, stream>>>(row, col, tag, part_row, start, scol,
                                                E, EPB, SB, z16, dis, n);
    k_agg<<<(n + 3) / 4, NT, 0, stream>>>(z16, scol, start, dis, b, out, n);
}

// Round 13
// 79.047 us; speedup vs baseline: 1.1132x; 1.1132x over previous
//
#include <hip/hip_runtime.h>
#include <hip/hip_bf16.h>
#include <hip/hip_fp16.h>

#define C 128        // C_IN == C_OUT == 128
#define NCH 32768    // nodes per LDS chunk (2^15), u8-packed counters -> 32 KiB LDS
#define CN 2         // chunks: 2*32768 = 65536 >= n (50000)
#define CNODES (CN * NCH)
#define BE 64        // edge chunks per side

typedef _Float16 f16x8 __attribute__((ext_vector_type(8)));
typedef _Float16 f16x4 __attribute__((ext_vector_type(4)));
typedef float f32x4 __attribute__((ext_vector_type(4)));

// ============================================================================
// Dispatch 1: blocks [0, 2*CN*BE): LDS-privatized u8 histograms (round-8);
//             blocks [2*CN*BE, +FB): fill scol with dummy 'n' + zero z16 row n.
// ============================================================================
__global__ __launch_bounds__(256) void k_hist(
        const int* __restrict__ row, const int* __restrict__ col,
        unsigned char* __restrict__ part_row, unsigned char* __restrict__ part_col,
        unsigned char* __restrict__ tag, int E,
        int* __restrict__ scol, int cap4, __half* __restrict__ Z16, int n) {
    __shared__ unsigned lh[NCH / 4];   // 8192 words = 32 KiB
    int bid = blockIdx.x;
    int tid = threadIdx.x;
    if (bid >= 2 * CN * BE) {
        // ---- fill blocks: scol = n everywhere (padded-CSR dummies) ----
        int fb = bid - 2 * CN * BE;
        int idx = fb * 256 + tid;          // int4 index
        if (idx < cap4) {
            int4 nv = make_int4(n, n, n, n);
            ((int4*)scol)[idx] = nv;
        }
        if (fb == 0 && tid < 16) {          // zero dummy z-row n (256 B)
            ((uint4*)(Z16 + (size_t)n * C))[tid] = make_uint4(0u, 0u, 0u, 0u);
        }
        return;
    }
    int side = (bid >= CN * BE) ? 1 : 0;
    int lb = side ? bid - CN * BE : bid;
    int c = lb >> 6;          // / BE  (0..CN-1)
    int b = lb & (BE - 1);
    for (int i = tid * 4; i < NCH / 4; i += 1024) {
        lh[i] = 0u; lh[i + 1] = 0u; lh[i + 2] = 0u; lh[i + 3] = 0u;
    }
    __syncthreads();
    int EPB = (E + BE - 1) / BE;
    int base = b * EPB;
    int end = min(base + EPB, E);
    const int* src = side ? col : row;

#define PROC_ROW(rv, ev)                                                  \
    if (((unsigned)(rv) >> 15) == (unsigned)c) {                          \
        int loc = (rv) & (NCH - 1);                                       \
        unsigned sh = ((unsigned)loc & 3u) << 3;                          \
        unsigned old = atomicAdd(&lh[loc >> 2], 1u << sh);                \
        tag[ev] = (unsigned char)((old >> sh) & 0xffu);                   \
    }
#define PROC_COL(rv)                                                      \
    if (((unsigned)(rv) >> 15) == (unsigned)c) {                          \
        int loc = (rv) & (NCH - 1);                                       \
        atomicAdd(&lh[loc >> 2], 1u << (((unsigned)loc & 3u) << 3));      \
    }
    int nv = 0;
    if ((((uintptr_t)(src + base)) & 15) == 0) nv = (end - base) >> 2;
    const int4* src4 = (const int4*)(src + base);
    if (!side) {
        for (int it = tid; it < nv; it += 256) {
            int4 v = src4[it];
            int e0 = base + it * 4;
            PROC_ROW(v.x, e0);
            PROC_ROW(v.y, e0 + 1);
            PROC_ROW(v.z, e0 + 2);
            PROC_ROW(v.w, e0 + 3);
        }
        for (int e = base + nv * 4 + tid; e < end; e += 256) {
            int r = src[e];
            PROC_ROW(r, e);
        }
    } else {
        for (int it = tid; it < nv; it += 256) {
            int4 v = src4[it];
            PROC_COL(v.x);
            PROC_COL(v.y);
            PROC_COL(v.z);
            PROC_COL(v.w);
        }
        for (int e = base + nv * 4 + tid; e < end; e += 256) {
            int r = src[e];
            PROC_COL(r);
        }
    }
#undef PROC_ROW
#undef PROC_COL
    __syncthreads();
    unsigned* dst = (unsigned*)((side ? part_col : part_row) + (size_t)b * CNODES + c * NCH);
    for (int i = tid; i < NCH / 4; i += 256) dst[i] = lh[i];
}

// ---- per-node: real row total + in-place exclusive u8 offsets; dis;
//      block scan over PADDED counts (ceil(deg/16)*16) ----
__global__ __launch_bounds__(256) void k_reduce_scan(
        unsigned char* __restrict__ part_row, const unsigned char* __restrict__ part_col,
        unsigned* __restrict__ start, unsigned* __restrict__ bsum,
        float* __restrict__ dis, int n) {
    __shared__ unsigned s[256];
    int t = threadIdx.x;
    int i = blockIdx.x * 256 + t;
    unsigned acc = 0;
    if (i < n) {
#pragma unroll 8
        for (int b = 0; b < BE; ++b) {
            size_t off = (size_t)b * CNODES + i;
            unsigned v = part_row[off];
            part_row[off] = (unsigned char)acc;
            acc += v;
        }
        unsigned d = 0;
#pragma unroll 8
        for (int b = 0; b < BE; ++b) d += part_col[(size_t)b * CNODES + i];
        dis[i] = rsqrtf((float)(d + 1u));
    }
    unsigned v = (i < n) ? ((acc + 15u) & ~15u) : 0u;   // padded count
    s[t] = v;
    __syncthreads();
    for (int off = 1; off < 256; off <<= 1) {
        unsigned add = (t >= off) ? s[t - off] : 0u;
        __syncthreads();
        s[t] += add;
        __syncthreads();
    }
    if (i <= n) start[i] = s[t] - v;     // exclusive (padded); start[n] = local tot
    if (t == 255) bsum[blockIdx.x] = s[t];
}

// ---- finalize: start[i] += sum(bsum[0..bid)) ----
__global__ __launch_bounds__(256) void k_scan_final(unsigned* __restrict__ start,
                                                    const unsigned* __restrict__ bsum,
                                                    int n) {
    __shared__ unsigned s[256];
    int t = threadIdx.x;
    int bid = blockIdx.x;
    s[t] = (t < bid) ? bsum[t] : 0u;     // NB <= 256
    __syncthreads();
    for (int off = 128; off > 0; off >>= 1) {
        if (t < off) s[t] += s[t + off];
        __syncthreads();
    }
    unsigned base = s[0];
    int i = bid * 256 + t;
    if (i <= n) start[i] += base;
}

// ============================================================================
// Fused: blocks [0,SB): atomic-free scatter (into padded segments);
//        [SB,SB+GB): MFMA GEMM with dis pre-scale: Z16 = dis*(x@W^T), fp16.
// ============================================================================
__global__ __launch_bounds__(256) void k_scatter_gemm(
        const int* __restrict__ row, const int* __restrict__ col,
        const unsigned char* __restrict__ tag, const unsigned char* __restrict__ boff,
        const unsigned* __restrict__ start, int* __restrict__ scol, int E, int SB,
        const float* __restrict__ A, const float* __restrict__ W,
        const float* __restrict__ dis, __half* __restrict__ Z16, int n) {
    __shared__ char lds[128 * 256];  // 32 KiB (gemm)
    int bid = blockIdx.x;
    int tid = threadIdx.x;
    if (bid < SB) {
        int e = bid * 256 + tid;
        if (e < E) {
            int EPB = (E + BE - 1) / BE;
            unsigned b = (unsigned)e / (unsigned)EPB;
            int r = row[e];
            unsigned p = start[r] + boff[(size_t)b * CNODES + r] + tag[e];
            scol[p] = col[e];
        }
        return;
    }
    // ---------------- GEMM ----------------
    int w = tid >> 6, lane = tid & 63;
    int m0 = (bid - SB) * 128;

#pragma unroll
    for (int i = 0; i < 16; ++i) {
        int fidx = i * 256 + tid;
        int nr = fidx >> 5;
        int c4 = fidx & 31;
        float4 wv = *(const float4*)(W + (size_t)nr * C + c4 * 4);
        f16x4 hh = {(_Float16)wv.x, (_Float16)wv.y, (_Float16)wv.z, (_Float16)wv.w};
        unsigned byte = (unsigned)(nr * 256 + c4 * 8);
        byte ^= (unsigned)((nr & 7) << 4);
        *(f16x4*)(lds + byte) = hh;
    }
    __syncthreads();

    int rbase = m0 + w * 32;
    int q = lane >> 4, rl = lane & 15;
    float dm[2];
#pragma unroll
    for (int mt = 0; mt < 2; ++mt) {
        int r = rbase + mt * 16 + rl;
        dm[mt] = (r < n) ? dis[r] : 0.f;
    }
    f32x4 acc[2][8] = {};
#pragma unroll
    for (int kc = 0; kc < 4; ++kc) {
        f16x8 af[2];
#pragma unroll
        for (int mt = 0; mt < 2; ++mt) {
            int r = rbase + mt * 16 + rl;
            float4 x0 = make_float4(0.f, 0.f, 0.f, 0.f), x1 = x0;
            if (r < n) {
                const float* srcx = A + (size_t)r * C + kc * 32 + q * 8;
                x0 = *(const float4*)srcx;
                x1 = *(const float4*)(srcx + 4);
            }
            float s = dm[mt];
            af[mt][0] = (_Float16)(x0.x * s);
            af[mt][1] = (_Float16)(x0.y * s);
            af[mt][2] = (_Float16)(x0.z * s);
            af[mt][3] = (_Float16)(x0.w * s);
            af[mt][4] = (_Float16)(x1.x * s);
            af[mt][5] = (_Float16)(x1.y * s);
            af[mt][6] = (_Float16)(x1.z * s);
            af[mt][7] = (_Float16)(x1.w * s);
        }
#pragma unroll
        for (int nt = 0; nt < 8; ++nt) {
            int nrow = nt * 16 + rl;
            unsigned byte = (unsigned)(nrow * 256 + kc * 64 + q * 16);
            byte ^= (unsigned)((nrow & 7) << 4);
            f16x8 bf = *(f16x8*)(lds + byte);
            acc[0][nt] = __builtin_amdgcn_mfma_f32_16x16x32_f16(af[0], bf, acc[0][nt], 0, 0, 0);
            acc[1][nt] = __builtin_amdgcn_mfma_f32_16x16x32_f16(af[1], bf, acc[1][nt], 0, 0, 0);
        }
    }
    __syncthreads();

#pragma unroll
    for (int mt = 0; mt < 2; ++mt)
#pragma unroll
        for (int nt = 0; nt < 8; ++nt)
#pragma unroll
            for (int i = 0; i < 4; ++i) {
                int row_l = w * 32 + mt * 16 + q * 4 + i;
                int colh = nt * 16 + rl;
                unsigned byte = (unsigned)(row_l * 256 + colh * 2);
                byte ^= (unsigned)((row_l & 7) << 4);
                *(_Float16*)(lds + byte) = (_Float16)acc[mt][nt][i];
            }
    __syncthreads();

#pragma unroll
    for (int it = 0; it < 8; ++it) {
        int idx = it * 256 + tid;
        int row_l = idx >> 4, c8 = idx & 15;
        unsigned byte = (unsigned)(row_l * 256 + c8 * 16);
        byte ^= (unsigned)((row_l & 7) << 4);
        uint4 v = *(uint4*)(lds + byte);
        int gr = m0 + row_l;
        if (gr < n) *(uint4*)(Z16 + (size_t)gr * C + c8 * 8) = v;
    }
}

// ============================================================================
// k_agg v4: out[r] = b + dis[r] * (z[r] + sum_seg z[scol[k]])   (z pre-scaled;
// segments padded to x16 with dummy node n whose z-row is zero).
// Wave = 4 edge-slots x 16 lanes; lane loads uint4 (8ch, 16 B); every
// iteration is a full 16-edge batch -> 4 outstanding loads/lane, no tails.
// ============================================================================
__device__ __forceinline__ void add8(uint4 v, float2& a0, float2& a1,
                                     float2& a2, float2& a3) {
    float2 f;
    f = __half22float2(*(__half2*)&v.x); a0.x += f.x; a0.y += f.y;
    f = __half22float2(*(__half2*)&v.y); a1.x += f.x; a1.y += f.y;
    f = __half22float2(*(__half2*)&v.z); a2.x += f.x; a2.y += f.y;
    f = __half22float2(*(__half2*)&v.w); a3.x += f.x; a3.y += f.y;
}

__global__ __launch_bounds__(256) void k_agg(const __half* __restrict__ Z16,
                                             const int* __restrict__ scol,
                                             const unsigned* __restrict__ start,
                                             const float* __restrict__ dis,
                                             const float* __restrict__ bias,
                                             float* __restrict__ out, int n) {
    int wid = threadIdx.x >> 6;
    int lane = threadIdx.x & 63;
    int slot = lane >> 4;          // 0..3 edge slot
    int g = lane & 15;             // 16 B group within 256 B row
    int r = blockIdx.x * 4 + wid;
    if (r >= n) return;
    unsigned s0 = start[r], s1 = start[r + 1];   // s1-s0 multiple of 16
    float dr = dis[r];
    const uint4* Z4 = (const uint4*)Z16;   // row stride = 16 uint4
    float2 a0 = {0.f, 0.f}, a1 = a0, a2 = a0, a3 = a0;
    if (slot == 0) {
        uint4 v = Z4[(size_t)r * 16 + g];  // self term
        add8(v, a0, a1, a2, a3);
    }
    for (unsigned k = s0; k < s1; k += 16) {
        int c0 = scol[k + slot];
        int c1 = scol[k + 4 + slot];
        int c2 = scol[k + 8 + slot];
        int c3 = scol[k + 12 + slot];
        uint4 v0 = Z4[(size_t)c0 * 16 + g];
        uint4 v1 = Z4[(size_t)c1 * 16 + g];
        uint4 v2 = Z4[(size_t)c2 * 16 + g];
        uint4 v3 = Z4[(size_t)c3 * 16 + g];
        add8(v0, a0, a1, a2, a3);
        add8(v1, a0, a1, a2, a3);
        add8(v2, a0, a1, a2, a3);
        add8(v3, a0, a1, a2, a3);
    }
    a0.x += __shfl_xor(a0.x, 16); a0.y += __shfl_xor(a0.y, 16);
    a1.x += __shfl_xor(a1.x, 16); a1.y += __shfl_xor(a1.y, 16);
    a2.x += __shfl_xor(a2.x, 16); a2.y += __shfl_xor(a2.y, 16);
    a3.x += __shfl_xor(a3.x, 16); a3.y += __shfl_xor(a3.y, 16);
    a0.x += __shfl_xor(a0.x, 32); a0.y += __shfl_xor(a0.y, 32);
    a1.x += __shfl_xor(a1.x, 32); a1.y += __shfl_xor(a1.y, 32);
    a2.x += __shfl_xor(a2.x, 32); a2.y += __shfl_xor(a2.y, 32);
    a3.x += __shfl_xor(a3.x, 32); a3.y += __shfl_xor(a3.y, 32);
    if (slot == 0) {
        float4 b0 = *(const float4*)(bias + g * 8);
        float4 b1 = *(const float4*)(bias + g * 8 + 4);
        float4 o0, o1;
        o0.x = b0.x + dr * a0.x; o0.y = b0.y + dr * a0.y;
        o0.z = b0.z + dr * a1.x; o0.w = b0.w + dr * a1.y;
        o1.x = b1.x + dr * a2.x; o1.y = b1.y + dr * a2.y;
        o1.z = b1.z + dr * a3.x; o1.w = b1.w + dr * a3.y;
        float* op = out + (size_t)r * C + g * 8;
        *(float4*)op = o0;
        *(float4*)(op + 4) = o1;
    }
}

extern "C" void kernel_launch(void* const* d_in, const int* in_sizes, int n_in,
                              void* d_out, int out_size, void* d_ws, size_t ws_size,
                              hipStream_t stream) {
    const float* x  = (const float*)d_in[0];
    const int*   ei = (const int*)d_in[1];   // [2, E] flat
    const float* W  = (const float*)d_in[2];
    const float* b  = (const float*)d_in[3];
    float* out = (float*)d_out;

    int n = in_sizes[0] / C;        // 50000 (requires n <= CNODES = 65536)
    int E = in_sizes[1] / 2;        // 800000
    const int* row = ei;
    const int* col = ei + E;

    // workspace layout (512B-aligned slabs), ~30 MB total
    char* p = (char*)d_ws;
    size_t cap  = (size_t)E + 15 * (size_t)n;   // padded scol capacity (1.55M)
    size_t sz_part = (((size_t)BE * CNODES) + 511) & ~(size_t)511;   // 4 MB (u8)
    size_t sz_n    = (((size_t)n * 4) + 511) & ~(size_t)511;
    size_t sz_n1   = (((size_t)(n + 1) * 4) + 511) & ~(size_t)511;
    size_t sz_E1   = (((size_t)E) + 511) & ~(size_t)511;
    size_t sz_cap  = ((cap * 4) + 511) & ~(size_t)511;
    size_t off = 0;
    unsigned char*  part_row = (unsigned char*)(p + off);  off += sz_part;
    unsigned char*  part_col = (unsigned char*)(p + off);  off += sz_part;
    unsigned*       start    = (unsigned*)(p + off);       off += sz_n1;
    float*          dis      = (float*)(p + off);          off += sz_n;
    unsigned*       bsum     = (unsigned*)(p + off);       off += 4096;
    unsigned char*  tag      = (unsigned char*)(p + off);  off += sz_E1;
    int*            scol     = (int*)(p + off);            off += sz_cap;
    __half*         z16      = (__half*)(p + off);         // (n+1)*C halves

    int NT = 256;
    int NB = (n + NT - 1) / NT;     // 196 <= 256
    int SB = (E + NT - 1) / NT;     // 3125
    int GB = (n + 127) / 128;       // 391
    int cap4 = (int)((cap + 3) / 4);          // int4 fill count
    int FB = (cap4 + NT - 1) / NT;            // fill blocks (~1514)

    k_hist<<<2 * CN * BE + FB, NT, 0, stream>>>(row, col, part_row, part_col, tag, E,
                                                scol, cap4, z16, n);
    k_reduce_scan<<<NB, NT, 0, stream>>>(part_row, part_col, start, bsum, dis, n);
    k_scan_final<<<NB, NT, 0, stream>>>(start, bsum, n);
    k_scatter_gemm<<<SB + GB, NT, 0, stream>>>(row, col, tag, part_row, start, scol,
                                               E, SB, x, W, dis, z16, n);
    k_agg<<<(n + 3) / 4, NT, 0, stream>>>(z16, scol, start, dis, b, out, n);
}

// Round 15
// 78.684 us; speedup vs baseline: 1.1184x; 1.0046x over previous
//
#include <hip/hip_runtime.h>
#include <hip/hip_bf16.h>
#include <hip/hip_fp16.h>

#define C 128        // C_IN == C_OUT == 128
#define NCH 32768    // nodes per LDS chunk (2^15), u8-packed counters -> 32 KiB LDS
#define CN 2         // chunks: 2*32768 = 65536 >= n (50000)
#define CNODES (CN * NCH)
#define BE 64        // edge chunks per side

typedef _Float16 f16x8 __attribute__((ext_vector_type(8)));
typedef _Float16 f16x4 __attribute__((ext_vector_type(4)));
typedef float f32x4 __attribute__((ext_vector_type(4)));

// ============================================================================
// Dispatch 1: blocks [0, 2*CN*BE): LDS-privatized u8 histograms;
//             blocks [2*CN*BE, +FB): fill scol dummies + zero z16 row n + gbase.
// ============================================================================
__global__ __launch_bounds__(256) void k_hist(
        const int* __restrict__ row, const int* __restrict__ col,
        unsigned char* __restrict__ part_row, unsigned char* __restrict__ part_col,
        unsigned char* __restrict__ tag, int E,
        int* __restrict__ scol, int cap4, __half* __restrict__ Z16,
        unsigned* __restrict__ gbase, int n) {
    __shared__ unsigned lh[NCH / 4];   // 8192 words = 32 KiB
    int bid = blockIdx.x;
    int tid = threadIdx.x;
    if (bid >= 2 * CN * BE) {
        // ---- fill blocks: scol = n everywhere (padded-CSR dummies) ----
        int fb = bid - 2 * CN * BE;
        int idx = fb * 256 + tid;          // int4 index
        if (idx < cap4) {
            int4 nv = make_int4(n, n, n, n);
            ((int4*)scol)[idx] = nv;
        }
        if (fb == 0) {
            if (tid < 16)                  // zero dummy z-row n (256 B)
                ((uint4*)(Z16 + (size_t)n * C))[tid] = make_uint4(0u, 0u, 0u, 0u);
            if (tid == 16) *gbase = 0u;    // reset scan base counter
        }
        return;
    }
    int side = (bid >= CN * BE) ? 1 : 0;
    int lb = side ? bid - CN * BE : bid;
    int c = lb >> 6;          // / BE  (0..CN-1)
    int b = lb & (BE - 1);
    for (int i = tid * 4; i < NCH / 4; i += 1024) {
        lh[i] = 0u; lh[i + 1] = 0u; lh[i + 2] = 0u; lh[i + 3] = 0u;
    }
    __syncthreads();
    int EPB = (E + BE - 1) / BE;
    int base = b * EPB;
    int end = min(base + EPB, E);
    const int* src = side ? col : row;

#define PROC_ROW(rv, ev)                                                  \
    if (((unsigned)(rv) >> 15) == (unsigned)c) {                          \
        int loc = (rv) & (NCH - 1);                                       \
        unsigned sh = ((unsigned)loc & 3u) << 3;                          \
        unsigned old = atomicAdd(&lh[loc >> 2], 1u << sh);                \
        tag[ev] = (unsigned char)((old >> sh) & 0xffu);                   \
    }
#define PROC_COL(rv)                                                      \
    if (((unsigned)(rv) >> 15) == (unsigned)c) {                          \
        int loc = (rv) & (NCH - 1);                                       \
        atomicAdd(&lh[loc >> 2], 1u << (((unsigned)loc & 3u) << 3));      \
    }
    int nv = 0;
    if ((((uintptr_t)(src + base)) & 15) == 0) nv = (end - base) >> 2;
    const int4* src4 = (const int4*)(src + base);
    if (!side) {
        for (int it = tid; it < nv; it += 256) {
            int4 v = src4[it];
            int e0 = base + it * 4;
            PROC_ROW(v.x, e0);
            PROC_ROW(v.y, e0 + 1);
            PROC_ROW(v.z, e0 + 2);
            PROC_ROW(v.w, e0 + 3);
        }
        for (int e = base + nv * 4 + tid; e < end; e += 256) {
            int r = src[e];
            PROC_ROW(r, e);
        }
    } else {
        for (int it = tid; it < nv; it += 256) {
            int4 v = src4[it];
            PROC_COL(v.x);
            PROC_COL(v.y);
            PROC_COL(v.z);
            PROC_COL(v.w);
        }
        for (int e = base + nv * 4 + tid; e < end; e += 256) {
            int r = src[e];
            PROC_COL(r);
        }
    }
#undef PROC_ROW
#undef PROC_COL
    __syncthreads();
    unsigned* dst = (unsigned*)((side ? part_col : part_row) + (size_t)b * CNODES + c * NCH);
    for (int i = tid; i < NCH / 4; i += 256) dst[i] = lh[i];
}

// ============================================================================
// k_reduce_scan (single-pass): per-node row total + in-place exclusive u8
// offsets; dis; block-scan of PADDED counts; block base via atomicAdd(gbase).
// Writes FINAL start[i] and pcnt[i] (padded segment length). Segment bases are
// arrival-ordered (disjoint, deterministic content per row).
// ============================================================================
__global__ __launch_bounds__(256) void k_reduce_scan(
        unsigned char* __restrict__ part_row, const unsigned char* __restrict__ part_col,
        unsigned* __restrict__ start, unsigned* __restrict__ pcnt,
        unsigned* __restrict__ gbase, float* __restrict__ dis, int n) {
    __shared__ unsigned s[256];
    __shared__ unsigned base_sh;
    int t = threadIdx.x;
    int i = blockIdx.x * 256 + t;
    unsigned acc = 0;
    if (i < n) {
#pragma unroll 8
        for (int b = 0; b < BE; ++b) {
            size_t off = (size_t)b * CNODES + i;
            unsigned v = part_row[off];
            part_row[off] = (unsigned char)acc;
            acc += v;
        }
        unsigned d = 0;
#pragma unroll 8
        for (int b = 0; b < BE; ++b) d += part_col[(size_t)b * CNODES + i];
        dis[i] = rsqrtf((float)(d + 1u));
    }
    unsigned v = (i < n) ? ((acc + 15u) & ~15u) : 0u;   // padded count
    s[t] = v;
    __syncthreads();
    for (int off = 1; off < 256; off <<= 1) {
        unsigned add = (t >= off) ? s[t - off] : 0u;
        __syncthreads();
        s[t] += add;
        __syncthreads();
    }
    if (t == 255) base_sh = atomicAdd(gbase, s[255]);
    __syncthreads();
    if (i < n) {
        start[i] = base_sh + s[t] - v;   // final exclusive base
        pcnt[i] = v;
    }
}

// ============================================================================
// Fused: blocks [0,SB): atomic-free scatter (into padded segments);
//        [SB,SB+GB): MFMA GEMM with dis pre-scale: Z16 = dis*(x@W^T), fp16.
// ============================================================================
__global__ __launch_bounds__(256) void k_scatter_gemm(
        const int* __restrict__ row, const int* __restrict__ col,
        const unsigned char* __restrict__ tag, const unsigned char* __restrict__ boff,
        const unsigned* __restrict__ start, int* __restrict__ scol, int E, int SB,
        const float* __restrict__ A, const float* __restrict__ W,
        const float* __restrict__ dis, __half* __restrict__ Z16, int n) {
    __shared__ char lds[128 * 256];  // 32 KiB (gemm)
    int bid = blockIdx.x;
    int tid = threadIdx.x;
    if (bid < SB) {
        int e = bid * 256 + tid;
        if (e < E) {
            int EPB = (E + BE - 1) / BE;
            unsigned b = (unsigned)e / (unsigned)EPB;
            int r = row[e];
            unsigned p = start[r] + boff[(size_t)b * CNODES + r] + tag[e];
            scol[p] = col[e];
        }
        return;
    }
    // ---------------- GEMM ----------------
    int w = tid >> 6, lane = tid & 63;
    int m0 = (bid - SB) * 128;

#pragma unroll
    for (int i = 0; i < 16; ++i) {
        int fidx = i * 256 + tid;
        int nr = fidx >> 5;
        int c4 = fidx & 31;
        float4 wv = *(const float4*)(W + (size_t)nr * C + c4 * 4);
        f16x4 hh = {(_Float16)wv.x, (_Float16)wv.y, (_Float16)wv.z, (_Float16)wv.w};
        unsigned byte = (unsigned)(nr * 256 + c4 * 8);
        byte ^= (unsigned)((nr & 7) << 4);
        *(f16x4*)(lds + byte) = hh;
    }
    __syncthreads();

    int rbase = m0 + w * 32;
    int q = lane >> 4, rl = lane & 15;
    float dm[2];
#pragma unroll
    for (int mt = 0; mt < 2; ++mt) {
        int r = rbase + mt * 16 + rl;
        dm[mt] = (r < n) ? dis[r] : 0.f;
    }
    f32x4 acc[2][8] = {};
#pragma unroll
    for (int kc = 0; kc < 4; ++kc) {
        f16x8 af[2];
#pragma unroll
        for (int mt = 0; mt < 2; ++mt) {
            int r = rbase + mt * 16 + rl;
            float4 x0 = make_float4(0.f, 0.f, 0.f, 0.f), x1 = x0;
            if (r < n) {
                const float* srcx = A + (size_t)r * C + kc * 32 + q * 8;
                x0 = *(const float4*)srcx;
                x1 = *(const float4*)(srcx + 4);
            }
            float s = dm[mt];
            af[mt][0] = (_Float16)(x0.x * s);
            af[mt][1] = (_Float16)(x0.y * s);
            af[mt][2] = (_Float16)(x0.z * s);
            af[mt][3] = (_Float16)(x0.w * s);
            af[mt][4] = (_Float16)(x1.x * s);
            af[mt][5] = (_Float16)(x1.y * s);
            af[mt][6] = (_Float16)(x1.z * s);
            af[mt][7] = (_Float16)(x1.w * s);
        }
#pragma unroll
        for (int nt = 0; nt < 8; ++nt) {
            int nrow = nt * 16 + rl;
            unsigned byte = (unsigned)(nrow * 256 + kc * 64 + q * 16);
            byte ^= (unsigned)((nrow & 7) << 4);
            f16x8 bf = *(f16x8*)(lds + byte);
            acc[0][nt] = __builtin_amdgcn_mfma_f32_16x16x32_f16(af[0], bf, acc[0][nt], 0, 0, 0);
            acc[1][nt] = __builtin_amdgcn_mfma_f32_16x16x32_f16(af[1], bf, acc[1][nt], 0, 0, 0);
        }
    }
    __syncthreads();

#pragma unroll
    for (int mt = 0; mt < 2; ++mt)
#pragma unroll
        for (int nt = 0; nt < 8; ++nt)
#pragma unroll
            for (int i = 0; i < 4; ++i) {
                int row_l = w * 32 + mt * 16 + q * 4 + i;
                int colh = nt * 16 + rl;
                unsigned byte = (unsigned)(row_l * 256 + colh * 2);
                byte ^= (unsigned)((row_l & 7) << 4);
                *(_Float16*)(lds + byte) = (_Float16)acc[mt][nt][i];
            }
    __syncthreads();

#pragma unroll
    for (int it = 0; it < 8; ++it) {
        int idx = it * 256 + tid;
        int row_l = idx >> 4, c8 = idx & 15;
        unsigned byte = (unsigned)(row_l * 256 + c8 * 16);
        byte ^= (unsigned)((row_l & 7) << 4);
        uint4 v = *(uint4*)(lds + byte);
        int gr = m0 + row_l;
        if (gr < n) *(uint4*)(Z16 + (size_t)gr * C + c8 * 8) = v;
    }
}

// ============================================================================
// k_agg v4: out[r] = b + dis[r] * (z[r] + sum_seg z[scol[k]])   (z pre-scaled;
// segments padded to x16 with dummy node n whose z-row is zero).
// Wave = 4 edge-slots x 16 lanes; lane loads uint4 (8ch, 16 B); every
// iteration is a full 16-edge batch -> 4 outstanding loads/lane, no tails.
// ============================================================================
__device__ __forceinline__ void add8(uint4 v, float2& a0, float2& a1,
                                     float2& a2, float2& a3) {
    float2 f;
    f = __half22float2(*(__half2*)&v.x); a0.x += f.x; a0.y += f.y;
    f = __half22float2(*(__half2*)&v.y); a1.x += f.x; a1.y += f.y;
    f = __half22float2(*(__half2*)&v.z); a2.x += f.x; a2.y += f.y;
    f = __half22float2(*(__half2*)&v.w); a3.x += f.x; a3.y += f.y;
}

__global__ __launch_bounds__(256) void k_agg(const __half* __restrict__ Z16,
                                             const int* __restrict__ scol,
                                             const unsigned* __restrict__ start,
                                             const unsigned* __restrict__ pcnt,
                                             const float* __restrict__ dis,
                                             const float* __restrict__ bias,
                                             float* __restrict__ out, int n) {
    int wid = threadIdx.x >> 6;
    int lane = threadIdx.x & 63;
    int slot = lane >> 4;          // 0..3 edge slot
    int g = lane & 15;             // 16 B group within 256 B row
    int r = blockIdx.x * 4 + wid;
    if (r >= n) return;
    unsigned s0 = start[r];
    unsigned s1 = s0 + pcnt[r];    // multiple of 16
    float dr = dis[r];
    const uint4* Z4 = (const uint4*)Z16;   // row stride = 16 uint4
    float2 a0 = {0.f, 0.f}, a1 = a0, a2 = a0, a3 = a0;
    if (slot == 0) {
        uint4 v = Z4[(size_t)r * 16 + g];  // self term
        add8(v, a0, a1, a2, a3);
    }
    for (unsigned k = s0; k < s1; k += 16) {
        int c0 = scol[k + slot];
        int c1 = scol[k + 4 + slot];
        int c2 = scol[k + 8 + slot];
        int c3 = scol[k + 12 + slot];
        uint4 v0 = Z4[(size_t)c0 * 16 + g];
        uint4 v1 = Z4[(size_t)c1 * 16 + g];
        uint4 v2 = Z4[(size_t)c2 * 16 + g];
        uint4 v3 = Z4[(size_t)c3 * 16 + g];
        add8(v0, a0, a1, a2, a3);
        add8(v1, a0, a1, a2, a3);
        add8(v2, a0, a1, a2, a3);
        add8(v3, a0, a1, a2, a3);
    }
    a0.x += __shfl_xor(a0.x, 16); a0.y += __shfl_xor(a0.y, 16);
    a1.x += __shfl_xor(a1.x, 16); a1.y += __shfl_xor(a1.y, 16);
    a2.x += __shfl_xor(a2.x, 16); a2.y += __shfl_xor(a2.y, 16);
    a3.x += __shfl_xor(a3.x, 16); a3.y += __shfl_xor(a3.y, 16);
    a0.x += __shfl_xor(a0.x, 32); a0.y += __shfl_xor(a0.y, 32);
    a1.x += __shfl_xor(a1.x, 32); a1.y += __shfl_xor(a1.y, 32);
    a2.x += __shfl_xor(a2.x, 32); a2.y += __shfl_xor(a2.y, 32);
    a3.x += __shfl_xor(a3.x, 32); a3.y += __shfl_xor(a3.y, 32);
    if (slot == 0) {
        float4 b0 = *(const float4*)(bias + g * 8);
        float4 b1 = *(const float4*)(bias + g * 8 + 4);
        float4 o0, o1;
        o0.x = b0.x + dr * a0.x; o0.y = b0.y + dr * a0.y;
        o0.z = b0.z + dr * a1.x; o0.w = b0.w + dr * a1.y;
        o1.x = b1.x + dr * a2.x; o1.y = b1.y + dr * a2.y;
        o1.z = b1.z + dr * a3.x; o1.w = b1.w + dr * a3.y;
        float* op = out + (size_t)r * C + g * 8;
        *(float4*)op = o0;
        *(float4*)(op + 4) = o1;
    }
}

extern "C" void kernel_launch(void* const* d_in, const int* in_sizes, int n_in,
                              void* d_out, int out_size, void* d_ws, size_t ws_size,
                              hipStream_t stream) {
    const float* x  = (const float*)d_in[0];
    const int*   ei = (const int*)d_in[1];   // [2, E] flat
    const float* W  = (const float*)d_in[2];
    const float* b  = (const float*)d_in[3];
    float* out = (float*)d_out;

    int n = in_sizes[0] / C;        // 50000 (requires n <= CNODES = 65536)
    int E = in_sizes[1] / 2;        // 800000
    const int* row = ei;
    const int* col = ei + E;

    // workspace layout (512B-aligned slabs), ~30 MB total
    char* p = (char*)d_ws;
    size_t cap  = (size_t)E + 15 * (size_t)n;   // padded scol capacity (1.55M)
    size_t sz_part = (((size_t)BE * CNODES) + 511) & ~(size_t)511;   // 4 MB (u8)
    size_t sz_n    = (((size_t)n * 4) + 511) & ~(size_t)511;
    size_t sz_E1   = (((size_t)E) + 511) & ~(size_t)511;
    size_t sz_cap  = ((cap * 4) + 511) & ~(size_t)511;
    size_t off = 0;
    unsigned char*  part_row = (unsigned char*)(p + off);  off += sz_part;
    unsigned char*  part_col = (unsigned char*)(p + off);  off += sz_part;
    unsigned*       start    = (unsigned*)(p + off);       off += sz_n;
    unsigned*       pcnt     = (unsigned*)(p + off);       off += sz_n;
    float*          dis      = (float*)(p + off);          off += sz_n;
    unsigned*       gbase    = (unsigned*)(p + off);       off += 512;
    unsigned char*  tag      = (unsigned char*)(p + off);  off += sz_E1;
    int*            scol     = (int*)(p + off);            off += sz_cap;
    __half*         z16      = (__half*)(p + off);         // (n+1)*C halves

    int NT = 256;
    int NB = (n + NT - 1) / NT;     // 196 <= 256
    int SB = (E + NT - 1) / NT;     // 3125
    int GB = (n + 127) / 128;       // 391
    int cap4 = (int)((cap + 3) / 4);          // int4 fill count
    int FB = (cap4 + NT - 1) / NT;            // fill blocks (~1514)

    k_hist<<<2 * CN * BE + FB, NT, 0, stream>>>(row, col, part_row, part_col, tag, E,
                                                scol, cap4, z16, gbase, n);
    k_reduce_scan<<<NB, NT, 0, stream>>>(part_row, part_col, start, pcnt, gbase, dis, n);
    k_scatter_gemm<<<SB + GB, NT, 0, stream>>>(row, col, tag, part_row, start, scol,
                                               E, SB, x, W, dis, z16, n);
    k_agg<<<(n + 3) / 4, NT, 0, stream>>>(z16, scol, start, pcnt, dis, b, out, n);
}

// Round 16
// 76.819 us; speedup vs baseline: 1.1455x; 1.0243x over previous
//
#include <hip/hip_runtime.h>
#include <hip/hip_bf16.h>
#include <hip/hip_fp16.h>

#define C 128        // C_IN == C_OUT == 128
#define NCH 32768    // nodes per LDS chunk (2^15), u8-packed counters -> 32 KiB LDS
#define CN 2         // chunks: 2*32768 = 65536 >= n (50000)
#define CNODES (CN * NCH)
#define BE 64        // edge chunks per side

typedef _Float16 f16x8 __attribute__((ext_vector_type(8)));
typedef _Float16 f16x4 __attribute__((ext_vector_type(4)));
typedef float f32x4 __attribute__((ext_vector_type(4)));

// ============================================================================
// Dispatch 1: blocks [0, 2*CN*BE): LDS-privatized u8 histograms;
//             blocks [2*CN*BE, +FB): fill scol dummies + zero z rows + gbase.
// ============================================================================
__global__ __launch_bounds__(256) void k_hist(
        const int* __restrict__ row, const int* __restrict__ col,
        unsigned char* __restrict__ part_row, unsigned char* __restrict__ part_col,
        unsigned char* __restrict__ tag, int E,
        int* __restrict__ scol, int cap4, __half* __restrict__ Z16,
        unsigned* __restrict__ gbase, int n) {
    __shared__ unsigned lh[NCH / 4];   // 8192 words = 32 KiB
    int bid = blockIdx.x;
    int tid = threadIdx.x;
    if (bid >= 2 * CN * BE) {
        // ---- fill blocks: scol = n everywhere (padded-CSR dummies) ----
        int fb = bid - 2 * CN * BE;
        int idx = fb * 256 + tid;          // int4 index
        if (idx < cap4) {
            int4 nv = make_int4(n, n, n, n);
            ((int4*)scol)[idx] = nv;
        }
        if (fb == 0) {
            if (tid < 16) {                // zero dummy row n in both passes
                int pass = tid >> 3, g = tid & 7;
                ((uint4*)(Z16 + ((size_t)pass * (n + 1) + n) * 64))[g] =
                    make_uint4(0u, 0u, 0u, 0u);
            }
            if (tid == 16) *gbase = 0u;    // reset scan base counter
        }
        return;
    }
    int side = (bid >= CN * BE) ? 1 : 0;
    int lb = side ? bid - CN * BE : bid;
    int c = lb >> 6;          // / BE  (0..CN-1)
    int b = lb & (BE - 1);
    for (int i = tid * 4; i < NCH / 4; i += 1024) {
        lh[i] = 0u; lh[i + 1] = 0u; lh[i + 2] = 0u; lh[i + 3] = 0u;
    }
    __syncthreads();
    int EPB = (E + BE - 1) / BE;
    int base = b * EPB;
    int end = min(base + EPB, E);
    const int* src = side ? col : row;

#define PROC_ROW(rv, ev)                                                  \
    if (((unsigned)(rv) >> 15) == (unsigned)c) {                          \
        int loc = (rv) & (NCH - 1);                                       \
        unsigned sh = ((unsigned)loc & 3u) << 3;                          \
        unsigned old = atomicAdd(&lh[loc >> 2], 1u << sh);                \
        tag[ev] = (unsigned char)((old >> sh) & 0xffu);                   \
    }
#define PROC_COL(rv)                                                      \
    if (((unsigned)(rv) >> 15) == (unsigned)c) {                          \
        int loc = (rv) & (NCH - 1);                                       \
        atomicAdd(&lh[loc >> 2], 1u << (((unsigned)loc & 3u) << 3));      \
    }
    int nv = 0;
    if ((((uintptr_t)(src + base)) & 15) == 0) nv = (end - base) >> 2;
    const int4* src4 = (const int4*)(src + base);
    if (!side) {
        for (int it = tid; it < nv; it += 256) {
            int4 v = src4[it];
            int e0 = base + it * 4;
            PROC_ROW(v.x, e0);
            PROC_ROW(v.y, e0 + 1);
            PROC_ROW(v.z, e0 + 2);
            PROC_ROW(v.w, e0 + 3);
        }
        for (int e = base + nv * 4 + tid; e < end; e += 256) {
            int r = src[e];
            PROC_ROW(r, e);
        }
    } else {
        for (int it = tid; it < nv; it += 256) {
            int4 v = src4[it];
            PROC_COL(v.x);
            PROC_COL(v.y);
            PROC_COL(v.z);
            PROC_COL(v.w);
        }
        for (int e = base + nv * 4 + tid; e < end; e += 256) {
            int r = src[e];
            PROC_COL(r);
        }
    }
#undef PROC_ROW
#undef PROC_COL
    __syncthreads();
    unsigned* dst = (unsigned*)((side ? part_col : part_row) + (size_t)b * CNODES + c * NCH);
    for (int i = tid; i < NCH / 4; i += 256) dst[i] = lh[i];
}

// ============================================================================
// k_reduce_scan (single-pass): per-node row total + in-place exclusive u8
// offsets; dis; block-scan of PADDED counts; block base via atomicAdd(gbase).
// ============================================================================
__global__ __launch_bounds__(256) void k_reduce_scan(
        unsigned char* __restrict__ part_row, const unsigned char* __restrict__ part_col,
        unsigned* __restrict__ start, unsigned* __restrict__ pcnt,
        unsigned* __restrict__ gbase, float* __restrict__ dis, int n) {
    __shared__ unsigned s[256];
    __shared__ unsigned base_sh;
    int t = threadIdx.x;
    int i = blockIdx.x * 256 + t;
    unsigned acc = 0;
    if (i < n) {
#pragma unroll 8
        for (int b = 0; b < BE; ++b) {
            size_t off = (size_t)b * CNODES + i;
            unsigned v = part_row[off];
            part_row[off] = (unsigned char)acc;
            acc += v;
        }
        unsigned d = 0;
#pragma unroll 8
        for (int b = 0; b < BE; ++b) d += part_col[(size_t)b * CNODES + i];
        dis[i] = rsqrtf((float)(d + 1u));
    }
    unsigned v = (i < n) ? ((acc + 15u) & ~15u) : 0u;   // padded count
    s[t] = v;
    __syncthreads();
    for (int off = 1; off < 256; off <<= 1) {
        unsigned add = (t >= off) ? s[t - off] : 0u;
        __syncthreads();
        s[t] += add;
        __syncthreads();
    }
    if (t == 255) base_sh = atomicAdd(gbase, s[255]);
    __syncthreads();
    if (i < n) {
        start[i] = base_sh + s[t] - v;   // final exclusive base
        pcnt[i] = v;
    }
}

// ============================================================================
// Fused: blocks [0,SB): atomic-free scatter (into padded segments);
//        [SB,SB+GB): MFMA GEMM with dis pre-scale; output in 2-pass layout:
//          Z16[pass][m][64ch] = dis[m]*(x@W^T)[m][pass*64 + ch], fp16.
// ============================================================================
__global__ __launch_bounds__(256) void k_scatter_gemm(
        const int* __restrict__ row, const int* __restrict__ col,
        const unsigned char* __restrict__ tag, const unsigned char* __restrict__ boff,
        const unsigned* __restrict__ start, int* __restrict__ scol, int E, int SB,
        const float* __restrict__ A, const float* __restrict__ W,
        const float* __restrict__ dis, __half* __restrict__ Z16, int n) {
    __shared__ char lds[128 * 256];  // 32 KiB (gemm)
    int bid = blockIdx.x;
    int tid = threadIdx.x;
    if (bid < SB) {
        int e = bid * 256 + tid;
        if (e < E) {
            int EPB = (E + BE - 1) / BE;
            unsigned b = (unsigned)e / (unsigned)EPB;
            int r = row[e];
            unsigned p = start[r] + boff[(size_t)b * CNODES + r] + tag[e];
            scol[p] = col[e];
        }
        return;
    }
    // ---------------- GEMM ----------------
    int w = tid >> 6, lane = tid & 63;
    int m0 = (bid - SB) * 128;

#pragma unroll
    for (int i = 0; i < 16; ++i) {
        int fidx = i * 256 + tid;
        int nr = fidx >> 5;
        int c4 = fidx & 31;
        float4 wv = *(const float4*)(W + (size_t)nr * C + c4 * 4);
        f16x4 hh = {(_Float16)wv.x, (_Float16)wv.y, (_Float16)wv.z, (_Float16)wv.w};
        unsigned byte = (unsigned)(nr * 256 + c4 * 8);
        byte ^= (unsigned)((nr & 7) << 4);
        *(f16x4*)(lds + byte) = hh;
    }
    __syncthreads();

    int rbase = m0 + w * 32;
    int q = lane >> 4, rl = lane & 15;
    float dm[2];
#pragma unroll
    for (int mt = 0; mt < 2; ++mt) {
        int r = rbase + mt * 16 + rl;
        dm[mt] = (r < n) ? dis[r] : 0.f;
    }
    f32x4 acc[2][8] = {};
#pragma unroll
    for (int kc = 0; kc < 4; ++kc) {
        f16x8 af[2];
#pragma unroll
        for (int mt = 0; mt < 2; ++mt) {
            int r = rbase + mt * 16 + rl;
            float4 x0 = make_float4(0.f, 0.f, 0.f, 0.f), x1 = x0;
            if (r < n) {
                const float* srcx = A + (size_t)r * C + kc * 32 + q * 8;
                x0 = *(const float4*)srcx;
                x1 = *(const float4*)(srcx + 4);
            }
            float s = dm[mt];
            af[mt][0] = (_Float16)(x0.x * s);
            af[mt][1] = (_Float16)(x0.y * s);
            af[mt][2] = (_Float16)(x0.z * s);
            af[mt][3] = (_Float16)(x0.w * s);
            af[mt][4] = (_Float16)(x1.x * s);
            af[mt][5] = (_Float16)(x1.y * s);
            af[mt][6] = (_Float16)(x1.z * s);
            af[mt][7] = (_Float16)(x1.w * s);
        }
#pragma unroll
        for (int nt = 0; nt < 8; ++nt) {
            int nrow = nt * 16 + rl;
            unsigned byte = (unsigned)(nrow * 256 + kc * 64 + q * 16);
            byte ^= (unsigned)((nrow & 7) << 4);
            f16x8 bf = *(f16x8*)(lds + byte);
            acc[0][nt] = __builtin_amdgcn_mfma_f32_16x16x32_f16(af[0], bf, acc[0][nt], 0, 0, 0);
            acc[1][nt] = __builtin_amdgcn_mfma_f32_16x16x32_f16(af[1], bf, acc[1][nt], 0, 0, 0);
        }
    }
    __syncthreads();

#pragma unroll
    for (int mt = 0; mt < 2; ++mt)
#pragma unroll
        for (int nt = 0; nt < 8; ++nt)
#pragma unroll
            for (int i = 0; i < 4; ++i) {
                int row_l = w * 32 + mt * 16 + q * 4 + i;
                int colh = nt * 16 + rl;
                unsigned byte = (unsigned)(row_l * 256 + colh * 2);
                byte ^= (unsigned)((row_l & 7) << 4);
                *(_Float16*)(lds + byte) = (_Float16)acc[mt][nt][i];
            }
    __syncthreads();

#pragma unroll
    for (int it = 0; it < 8; ++it) {
        int idx = it * 256 + tid;
        int row_l = idx >> 4, c8 = idx & 15;
        unsigned byte = (unsigned)(row_l * 256 + c8 * 16);
        byte ^= (unsigned)((row_l & 7) << 4);
        uint4 v = *(uint4*)(lds + byte);
        int gr = m0 + row_l;
        if (gr < n) {
            int pass = c8 >> 3;        // channel half
            int g = c8 & 7;            // 16 B group within half-row
            *(uint4*)(Z16 + ((size_t)pass * (n + 1) + gr) * 64 + g * 8) = v;
        }
    }
}

// ============================================================================
// k_agg v5: 2 channel passes (64 ch = 128 B rows, 6.4 MB/pass working set).
// Wave = 2 rows x (4 edge-slots x 8 lanes); lane loads uint4 (8 ch, 16 B);
// 16-edge batches, segments padded x16 -> 4 outstanding loads/lane (64 B),
// identical MLP to v4. Pass-major block order for L2 temporal locality.
// ============================================================================
__device__ __forceinline__ void add8(uint4 v, float2& a0, float2& a1,
                                     float2& a2, float2& a3) {
    float2 f;
    f = __half22float2(*(__half2*)&v.x); a0.x += f.x; a0.y += f.y;
    f = __half22float2(*(__half2*)&v.y); a1.x += f.x; a1.y += f.y;
    f = __half22float2(*(__half2*)&v.z); a2.x += f.x; a2.y += f.y;
    f = __half22float2(*(__half2*)&v.w); a3.x += f.x; a3.y += f.y;
}

__global__ __launch_bounds__(256) void k_agg(const __half* __restrict__ Z16,
                                             const int* __restrict__ scol,
                                             const unsigned* __restrict__ start,
                                             const unsigned* __restrict__ pcnt,
                                             const float* __restrict__ dis,
                                             const float* __restrict__ bias,
                                             float* __restrict__ out, int n, int RPB) {
    int bid = blockIdx.x;
    int pass = (bid >= RPB) ? 1 : 0;
    int rb = bid - pass * RPB;
    int wid = threadIdx.x >> 6;
    int lane = threadIdx.x & 63;
    int rw = lane >> 5;            // row within the wave's pair
    int slot = (lane >> 3) & 3;    // 0..3 edge slot
    int g = lane & 7;              // 16 B group within 128 B half-row
    int r = rb * 8 + wid * 2 + rw;
    if (r >= n) return;
    unsigned s0 = start[r];
    unsigned s1 = s0 + pcnt[r];    // multiple of 16
    float dr = dis[r];
    const uint4* Z4 = (const uint4*)(Z16 + (size_t)pass * (n + 1) * 64);  // 8 uint4/row
    float2 a0 = {0.f, 0.f}, a1 = a0, a2 = a0, a3 = a0;
    if (slot == 0) {
        uint4 v = Z4[(size_t)r * 8 + g];   // self term
        add8(v, a0, a1, a2, a3);
    }
    for (unsigned k = s0; k < s1; k += 16) {
        int c0 = scol[k + slot];
        int c1 = scol[k + 4 + slot];
        int c2 = scol[k + 8 + slot];
        int c3 = scol[k + 12 + slot];
        uint4 v0 = Z4[(size_t)c0 * 8 + g];
        uint4 v1 = Z4[(size_t)c1 * 8 + g];
        uint4 v2 = Z4[(size_t)c2 * 8 + g];
        uint4 v3 = Z4[(size_t)c3 * 8 + g];
        add8(v0, a0, a1, a2, a3);
        add8(v1, a0, a1, a2, a3);
        add8(v2, a0, a1, a2, a3);
        add8(v3, a0, a1, a2, a3);
    }
    // reduce across the 4 slots (lane bits 3,4) — stays within each 32-lane half
    a0.x += __shfl_xor(a0.x, 8);  a0.y += __shfl_xor(a0.y, 8);
    a1.x += __shfl_xor(a1.x, 8);  a1.y += __shfl_xor(a1.y, 8);
    a2.x += __shfl_xor(a2.x, 8);  a2.y += __shfl_xor(a2.y, 8);
    a3.x += __shfl_xor(a3.x, 8);  a3.y += __shfl_xor(a3.y, 8);
    a0.x += __shfl_xor(a0.x, 16); a0.y += __shfl_xor(a0.y, 16);
    a1.x += __shfl_xor(a1.x, 16); a1.y += __shfl_xor(a1.y, 16);
    a2.x += __shfl_xor(a2.x, 16); a2.y += __shfl_xor(a2.y, 16);
    a3.x += __shfl_xor(a3.x, 16); a3.y += __shfl_xor(a3.y, 16);
    if (slot == 0) {
        const float* bp = bias + pass * 64 + g * 8;
        float4 b0 = *(const float4*)bp;
        float4 b1 = *(const float4*)(bp + 4);
        float4 o0, o1;
        o0.x = b0.x + dr * a0.x; o0.y = b0.y + dr * a0.y;
        o0.z = b0.z + dr * a1.x; o0.w = b0.w + dr * a1.y;
        o1.x = b1.x + dr * a2.x; o1.y = b1.y + dr * a2.y;
        o1.z = b1.z + dr * a3.x; o1.w = b1.w + dr * a3.y;
        float* op = out + (size_t)r * C + pass * 64 + g * 8;
        *(float4*)op = o0;
        *(float4*)(op + 4) = o1;
    }
}

extern "C" void kernel_launch(void* const* d_in, const int* in_sizes, int n_in,
                              void* d_out, int out_size, void* d_ws, size_t ws_size,
                              hipStream_t stream) {
    const float* x  = (const float*)d_in[0];
    const int*   ei = (const int*)d_in[1];   // [2, E] flat
    const float* W  = (const float*)d_in[2];
    const float* b  = (const float*)d_in[3];
    float* out = (float*)d_out;

    int n = in_sizes[0] / C;        // 50000 (requires n <= CNODES = 65536)
    int E = in_sizes[1] / 2;        // 800000
    const int* row = ei;
    const int* col = ei + E;

    // workspace layout (512B-aligned slabs), ~30 MB total
    char* p = (char*)d_ws;
    size_t cap  = (size_t)E + 15 * (size_t)n;   // padded scol capacity (1.55M)
    size_t sz_part = (((size_t)BE * CNODES) + 511) & ~(size_t)511;   // 4 MB (u8)
    size_t sz_n    = (((size_t)n * 4) + 511) & ~(size_t)511;
    size_t sz_E1   = (((size_t)E) + 511) & ~(size_t)511;
    size_t sz_cap  = ((cap * 4) + 511) & ~(size_t)511;
    size_t off = 0;
    unsigned char*  part_row = (unsigned char*)(p + off);  off += sz_part;
    unsigned char*  part_col = (unsigned char*)(p + off);  off += sz_part;
    unsigned*       start    = (unsigned*)(p + off);       off += sz_n;
    unsigned*       pcnt     = (unsigned*)(p + off);       off += sz_n;
    float*          dis      = (float*)(p + off);          off += sz_n;
    unsigned*       gbase    = (unsigned*)(p + off);       off += 512;
    unsigned char*  tag      = (unsigned char*)(p + off);  off += sz_E1;
    int*            scol     = (int*)(p + off);            off += sz_cap;
    __half*         z16      = (__half*)(p + off);         // 2*(n+1)*64 halves

    int NT = 256;
    int NB = (n + NT - 1) / NT;     // 196 <= 256
    int SB = (E + NT - 1) / NT;     // 3125
    int GB = (n + 127) / 128;       // 391
    int cap4 = (int)((cap + 3) / 4);          // int4 fill count
    int FB = (cap4 + NT - 1) / NT;            // fill blocks (~1514)
    int RPB = (n + 7) / 8;                    // 6250 row-blocks per pass

    k_hist<<<2 * CN * BE + FB, NT, 0, stream>>>(row, col, part_row, part_col, tag, E,
                                                scol, cap4, z16, gbase, n);
    k_reduce_scan<<<NB, NT, 0, stream>>>(part_row, part_col, start, pcnt, gbase, dis, n);
    k_scatter_gemm<<<SB + GB, NT, 0, stream>>>(row, col, tag, part_row, start, scol,
                                               E, SB, x, W, dis, z16, n);
    k_agg<<<2 * RPB, NT, 0, stream>>>(z16, scol, start, pcnt, dis, b, out, n, RPB);
}